// Round 1
// baseline (1517.645 us; speedup 1.0000x reference)
//
#include <hip/hip_runtime.h>
#include <stdint.h>

// Problem constants
#define BB   4
#define NN   16384
#define HH   8
#define DD   512
#define HIDN 2048
#define ROWST (BB * NN)   // 65536 token rows

using short8 = __attribute__((ext_vector_type(8))) short;   // 8 bf16 (4 VGPRs)
using f32x4  = __attribute__((ext_vector_type(4))) float;   // MFMA acc

__device__ __forceinline__ float bf2f(uint16_t h) {
  union { uint32_t u; float f; } v; v.u = ((uint32_t)h) << 16; return v.f;
}
__device__ __forceinline__ uint16_t f2bf(float f) {
  union { float f; uint32_t u; } v; v.f = f;
  return (uint16_t)((v.u + 0x7FFFu + ((v.u >> 16) & 1u)) >> 16);  // RNE
}
__device__ __forceinline__ float gelu_f(float x) {  // tanh-approx gelu (jax default)
  float u = 0.7978845608028654f * (x + 0.044715f * x * x * x);
  u = fminf(10.f, fmaxf(-10.f, u));
  float e = __expf(-2.f * u);
  float t = (1.f - e) / (1.f + e);
  return 0.5f * x * (1.f + t);
}
// async global->LDS, 16B/lane; LDS dest = wave-uniform base + lane*16
__device__ __forceinline__ void cp16(const uint16_t* g, uint16_t* l) {
  __builtin_amdgcn_global_load_lds((const __attribute__((address_space(1))) void*)g,
                                   (__attribute__((address_space(3))) void*)l, 16, 0, 0);
}

// ---------------- GEMM: C[M,N] = A[M,K](bf16) * B^T[N,K](bf16) + epilogue ----------------
// E: 0 phi(elu+1)->bf16, 1 +bias->bf16, 2 +bias+res->bf16, 3 gelu->bf16, 4 +bias+res->f32
template <int E>
__launch_bounds__(256)
__global__ void gemm_bt(const uint16_t* __restrict__ A, const uint16_t* __restrict__ BT,
                        const float* __restrict__ bias, const uint16_t* __restrict__ res,
                        void* __restrict__ outp, int M, int N, int K) {
  __shared__ __align__(16) uint16_t As[128 * 64];
  __shared__ __align__(16) uint16_t Bs[128 * 64];
  const int tid = threadIdx.x;
  const int lane = tid & 63, wave = tid >> 6;
  const int l15 = lane & 15, l4 = lane >> 4;
  const int m0 = blockIdx.x * 128, n0 = blockIdx.y * 128;
  const int wm = (wave >> 1) * 64, wn = (wave & 1) * 64;

  f32x4 acc[4][4];
#pragma unroll
  for (int i = 0; i < 4; ++i)
#pragma unroll
    for (int j = 0; j < 4; ++j) acc[i][j] = (f32x4){0.f, 0.f, 0.f, 0.f};

  const int srow = tid >> 3;        // 0..31: row within 32-row staging slice
  const int skc  = (tid & 7) * 8;   // k element offset within row
  const uint16_t* ga = A  + (size_t)(m0 + srow) * K + skc;
  const uint16_t* gb = BT + (size_t)(n0 + srow) * K + skc;

  for (int kb = 0; kb < K; kb += 64) {
    __syncthreads();                 // all waves done reading previous tile
#pragma unroll
    for (int i = 0; i < 4; ++i) {    // stage A(128x64) and B^T(128x64), 16B/lane
      cp16(ga + (size_t)i * 32 * K + kb, &As[(i * 256 + wave * 64) * 8]);
      cp16(gb + (size_t)i * 32 * K + kb, &Bs[(i * 256 + wave * 64) * 8]);
    }
    __syncthreads();                 // compiler drains vmcnt before barrier
#pragma unroll
    for (int kk = 0; kk < 64; kk += 32) {
      short8 af[4], bfr[4];
#pragma unroll
      for (int i = 0; i < 4; ++i)
        af[i] = *(const short8*)&As[(wm + i * 16 + l15) * 64 + kk + l4 * 8];
#pragma unroll
      for (int j = 0; j < 4; ++j)
        bfr[j] = *(const short8*)&Bs[(wn + j * 16 + l15) * 64 + kk + l4 * 8];
#pragma unroll
      for (int i = 0; i < 4; ++i)
#pragma unroll
        for (int j = 0; j < 4; ++j)
          acc[i][j] = __builtin_amdgcn_mfma_f32_16x16x32_bf16(af[i], bfr[j], acc[i][j], 0, 0, 0);
    }
  }

  uint16_t* outb = (uint16_t*)outp;
  float* outf = (float*)outp;
#pragma unroll
  for (int i = 0; i < 4; ++i)
#pragma unroll
    for (int r = 0; r < 4; ++r) {
      const int row = m0 + wm + i * 16 + l4 * 4 + r;   // C/D: row = quad*4+reg
#pragma unroll
      for (int j = 0; j < 4; ++j) {
        const int col = n0 + wn + j * 16 + l15;        // C/D: col = lane&15
        float v = acc[i][j][r] + bias[col];
        const size_t idx = (size_t)row * N + col;
        if (E == 0)      { v = v > 0.f ? v + 1.f : __expf(v); outb[idx] = f2bf(v); }
        else if (E == 1) { outb[idx] = f2bf(v); }
        else if (E == 2) { v += bf2f(res[idx]); outb[idx] = f2bf(v); }
        else if (E == 3) { outb[idx] = f2bf(gelu_f(v)); }
        else             { v += bf2f(res[idx]); outf[idx] = v; }
      }
    }
}

// ---------------- LayerNorm: one wave per 512-elem row, out bf16 ----------------
template <int BFIN>
__launch_bounds__(256)
__global__ void ln_kernel(const void* __restrict__ inp, const float* __restrict__ gam,
                          const float* __restrict__ bet, uint16_t* __restrict__ out) {
  const int row = blockIdx.x * 4 + (threadIdx.x >> 6);
  const int lane = threadIdx.x & 63;
  const size_t base = (size_t)row * DD + lane * 8;
  float x[8];
  if (BFIN) {
    const uint4 u = *(const uint4*)((const uint16_t*)inp + base);
    x[0] = bf2f((uint16_t)(u.x & 0xffff)); x[1] = bf2f((uint16_t)(u.x >> 16));
    x[2] = bf2f((uint16_t)(u.y & 0xffff)); x[3] = bf2f((uint16_t)(u.y >> 16));
    x[4] = bf2f((uint16_t)(u.z & 0xffff)); x[5] = bf2f((uint16_t)(u.z >> 16));
    x[6] = bf2f((uint16_t)(u.w & 0xffff)); x[7] = bf2f((uint16_t)(u.w >> 16));
  } else {
    const float* f = (const float*)inp + base;
    const float4 a = *(const float4*)f;
    const float4 b = *(const float4*)(f + 4);
    x[0]=a.x; x[1]=a.y; x[2]=a.z; x[3]=a.w; x[4]=b.x; x[5]=b.y; x[6]=b.z; x[7]=b.w;
  }
  float s = 0.f, s2 = 0.f;
#pragma unroll
  for (int j = 0; j < 8; ++j) { s += x[j]; s2 += x[j] * x[j]; }
#pragma unroll
  for (int off = 32; off; off >>= 1) { s += __shfl_xor(s, off, 64); s2 += __shfl_xor(s2, off, 64); }
  const float m = s * (1.f / DD);
  const float rs = rsqrtf(s2 * (1.f / DD) - m * m + 1e-5f);
  uint16_t o[8];
#pragma unroll
  for (int j = 0; j < 8; ++j) {
    const int col = lane * 8 + j;
    o[j] = f2bf((x[j] - m) * rs * gam[col] + bet[col]);
  }
  uint4 w;
  w.x = (uint32_t)o[0] | ((uint32_t)o[1] << 16);
  w.y = (uint32_t)o[2] | ((uint32_t)o[3] << 16);
  w.z = (uint32_t)o[4] | ((uint32_t)o[5] << 16);
  w.w = (uint32_t)o[6] | ((uint32_t)o[7] << 16);
  *(uint4*)(out + base) = w;
}

// ---------------- weight transpose fp32[R,C] -> bf16[C,R] ----------------
__launch_bounds__(256)
__global__ void transpose_bf(const float* __restrict__ in, uint16_t* __restrict__ out,
                             int R, int C) {
  __shared__ float tile[32][33];
  const int tx = threadIdx.x, ty = threadIdx.y;
  const int c0 = blockIdx.x * 32, r0 = blockIdx.y * 32;
#pragma unroll
  for (int i = 0; i < 32; i += 8)
    tile[ty + i][tx] = in[(size_t)(r0 + ty + i) * C + (c0 + tx)];
  __syncthreads();
#pragma unroll
  for (int i = 0; i < 32; i += 8)
    out[(size_t)(c0 + ty + i) * R + (r0 + tx)] = f2bf(tile[tx][ty + i]);
}

// ---------------- kv[b,h,dk,dv] = sum_n pk*v ; ksum[b,h,dk] = sum_n pk ----------------
__launch_bounds__(256)
__global__ void kv_kernel(const uint16_t* __restrict__ pk, const uint16_t* __restrict__ v,
                          float* __restrict__ kv, float* __restrict__ ksum) {
  const int bh = blockIdx.x;                // b*8+h
  const int b = bh >> 3, h = bh & 7;
  const int n0 = blockIdx.y * 1024;
  const int t = threadIdx.x;
  const int dk = t >> 2, sub = t & 3, dv0 = sub * 16;
  __shared__ float pf[8][64];
  __shared__ float vf[8][64];
  float acc[16];
#pragma unroll
  for (int j = 0; j < 16; ++j) acc[j] = 0.f;
  float ks = 0.f;
  const int e = t * 4;
  const bool isPk = (e < 512);
  const int er = (isPk ? e : e - 512) >> 6;
  const int ec = e & 63;
  const uint16_t* srcBase = isPk ? pk : v;
  for (int it = 0; it < 1024; it += 8) {
    __syncthreads();
    const ushort4 d = *(const ushort4*)(srcBase +
        (((size_t)(b * NN + n0 + it + er)) * HH + h) * 64 + ec);
    float* dst = isPk ? &pf[er][ec] : &vf[er][ec];
    dst[0] = bf2f(d.x); dst[1] = bf2f(d.y); dst[2] = bf2f(d.z); dst[3] = bf2f(d.w);
    __syncthreads();
#pragma unroll
    for (int r = 0; r < 8; ++r) {
      const float p = pf[r][dk];
      if (sub == 0) ks += p;
      const float4 v0 = *(const float4*)&vf[r][dv0];
      const float4 v1 = *(const float4*)&vf[r][dv0 + 4];
      const float4 v2 = *(const float4*)&vf[r][dv0 + 8];
      const float4 v3 = *(const float4*)&vf[r][dv0 + 12];
      acc[0]  += p * v0.x; acc[1]  += p * v0.y; acc[2]  += p * v0.z; acc[3]  += p * v0.w;
      acc[4]  += p * v1.x; acc[5]  += p * v1.y; acc[6]  += p * v1.z; acc[7]  += p * v1.w;
      acc[8]  += p * v2.x; acc[9]  += p * v2.y; acc[10] += p * v2.z; acc[11] += p * v2.w;
      acc[12] += p * v3.x; acc[13] += p * v3.y; acc[14] += p * v3.z; acc[15] += p * v3.w;
    }
  }
  float* kvp = kv + ((size_t)bh * 64 + dk) * 64 + dv0;
#pragma unroll
  for (int j = 0; j < 16; ++j) atomicAdd(kvp + j, acc[j]);
  if (sub == 0) atomicAdd(ksum + bh * 64 + dk, ks);
}

// ---------------- attn[b,n,h,dv] = (pq . kv[:,dv]) / (pq . ksum + eps) ----------------
__launch_bounds__(256)
__global__ void attn_kernel(const uint16_t* __restrict__ pq, const float* __restrict__ kv,
                            const float* __restrict__ ksum, uint16_t* __restrict__ attn) {
  const int bh = blockIdx.x, b = bh >> 3, h = bh & 7;
  const int n0 = blockIdx.y * 256;
  const int t = threadIdx.x, lane = t & 63, w = t >> 6;
  float kvr[64];                      // kv[dk][lane] per-lane column in registers
  const float* kvb = kv + (size_t)bh * 4096;
#pragma unroll
  for (int dk = 0; dk < 64; ++dk) kvr[dk] = kvb[dk * 64 + lane];
  const float ksl = ksum[bh * 64 + lane];
  __shared__ float pqs[4][64];
  for (int it = 0; it < 256; it += 4) {
    const int n = n0 + it + w;        // one row per wave
    const size_t ofs = (((size_t)(b * NN + n)) * HH + h) * 64 + lane;
    const float pv = bf2f(pq[ofs]);
    pqs[w][lane] = pv;                // wave-private row; in-order DS ops
    float a0 = 0.f, a1 = 0.f, a2 = 0.f, a3 = 0.f;
#pragma unroll
    for (int d4 = 0; d4 < 64; d4 += 4) {
      const float4 p4 = *(const float4*)&pqs[w][d4];   // LDS broadcast
      a0 += p4.x * kvr[d4];     a1 += p4.y * kvr[d4 + 1];
      a2 += p4.z * kvr[d4 + 2]; a3 += p4.w * kvr[d4 + 3];
    }
    float den = pv * ksl;
#pragma unroll
    for (int off = 32; off; off >>= 1) den += __shfl_xor(den, off, 64);
    attn[ofs] = f2bf((a0 + a1 + a2 + a3) / (den + 1e-6f));
  }
}

// ---------------- host launch ----------------
extern "C" void kernel_launch(void* const* d_in, const int* in_sizes, int n_in,
                              void* d_out, int out_size, void* d_ws, size_t ws_size,
                              hipStream_t stream) {
  (void)in_sizes; (void)n_in; (void)out_size;
  const float* x    = (const float*)d_in[0];
  const float* ln1g = (const float*)d_in[1];
  const float* ln1b = (const float*)d_in[2];
  const float* Wq   = (const float*)d_in[3];
  const float* bq   = (const float*)d_in[4];
  const float* Wk   = (const float*)d_in[5];
  const float* bk   = (const float*)d_in[6];
  const float* Wv   = (const float*)d_in[7];
  const float* bv   = (const float*)d_in[8];
  const float* Wo   = (const float*)d_in[9];
  const float* bo   = (const float*)d_in[10];
  const float* ln2g = (const float*)d_in[11];
  const float* ln2b = (const float*)d_in[12];
  const float* W1   = (const float*)d_in[13];
  const float* b1   = (const float*)d_in[14];
  const float* W2   = (const float*)d_in[15];
  const float* b2   = (const float*)d_in[16];

  if (ws_size < 411000000ULL) return;  // need ~391 MB; fail loudly via absmax

  char* p = (char*)d_ws;
  auto alloc = [&](size_t bytes) -> char* {
    char* r = p; p += (bytes + 255) & ~(size_t)255; return r;
  };
  uint16_t* Hb  = (uint16_t*)alloc((size_t)ROWST * DD * 2);   // h (LN1 out), bf16
  uint16_t* PQ  = (uint16_t*)alloc((size_t)ROWST * DD * 2);   // phi(q); later h2
  uint16_t* PK  = (uint16_t*)alloc((size_t)ROWST * DD * 2);   // phi(k); later hres
  uint16_t* PV  = (uint16_t*)alloc((size_t)ROWST * DD * 2);   // v; later attn
  uint16_t* U   = (uint16_t*)alloc((size_t)32768 * HIDN * 2); // MLP hidden chunk
  uint16_t* WqT = (uint16_t*)alloc((size_t)DD * DD * 2);
  uint16_t* WkT = (uint16_t*)alloc((size_t)DD * DD * 2);
  uint16_t* WvT = (uint16_t*)alloc((size_t)DD * DD * 2);
  uint16_t* WoT = (uint16_t*)alloc((size_t)DD * DD * 2);
  uint16_t* W1T = (uint16_t*)alloc((size_t)HIDN * DD * 2);
  uint16_t* W2T = (uint16_t*)alloc((size_t)DD * HIDN * 2);
  float*    KV  = (float*)alloc((size_t)(32 * 64 * 64 + 32 * 64) * 4);
  float*    KS  = KV + 32 * 64 * 64;

  const dim3 tb(32, 8);
  transpose_bf<<<dim3(16, 16), tb, 0, stream>>>(Wq, WqT, DD, DD);
  transpose_bf<<<dim3(16, 16), tb, 0, stream>>>(Wk, WkT, DD, DD);
  transpose_bf<<<dim3(16, 16), tb, 0, stream>>>(Wv, WvT, DD, DD);
  transpose_bf<<<dim3(16, 16), tb, 0, stream>>>(Wo, WoT, DD, DD);
  transpose_bf<<<dim3(64, 16), tb, 0, stream>>>(W1, W1T, DD, HIDN);
  transpose_bf<<<dim3(16, 64), tb, 0, stream>>>(W2, W2T, HIDN, DD);
  hipMemsetAsync(KV, 0, (size_t)(32 * 64 * 64 + 32 * 64) * 4, stream);

  // h = LN1(x)
  ln_kernel<0><<<ROWST / 4, 256, 0, stream>>>(x, ln1g, ln1b, Hb);
  // pq/pk = phi(h@W + b), v = h@Wv + bv
  gemm_bt<0><<<dim3(512, 4), 256, 0, stream>>>(Hb, WqT, bq, nullptr, PQ, ROWST, DD, DD);
  gemm_bt<0><<<dim3(512, 4), 256, 0, stream>>>(Hb, WkT, bk, nullptr, PK, ROWST, DD, DD);
  gemm_bt<1><<<dim3(512, 4), 256, 0, stream>>>(Hb, WvT, bv, nullptr, PV, ROWST, DD, DD);
  // kv / ksum reduction
  kv_kernel<<<dim3(32, 16), 256, 0, stream>>>(PK, PV, KV, KS);
  // attn (normalized) -> PV (v no longer needed)
  attn_kernel<<<dim3(32, 64), 256, 0, stream>>>(PQ, KV, KS, PV);
  // hres = attn@Wo + bo + h -> PK
  gemm_bt<2><<<dim3(512, 4), 256, 0, stream>>>(PV, WoT, bo, Hb, PK, ROWST, DD, DD);
  // h2 = LN2(hres) -> PQ
  ln_kernel<1><<<ROWST / 4, 256, 0, stream>>>(PK, ln2g, ln2b, PQ);
  // MLP in 2 row-chunks: out = h2 + gelu(h2@W1+b1)@W2 + b2
  for (int c = 0; c < 2; ++c) {
    const uint16_t* h2c = PQ + (size_t)c * 32768 * DD;
    gemm_bt<3><<<dim3(256, 16), 256, 0, stream>>>(h2c, W1T, b1, nullptr, U, 32768, HIDN, DD);
    gemm_bt<4><<<dim3(256, 4), 256, 0, stream>>>(U, W2T, b2, h2c,
        (float*)d_out + (size_t)c * 32768 * DD, 32768, DD, HIDN);
  }
}

// Round 2
// 1203.434 us; speedup vs baseline: 1.2611x; 1.2611x over previous
//
#include <hip/hip_runtime.h>
#include <stdint.h>

// Problem constants
#define BB   4
#define NN   16384
#define HH   8
#define DD   512
#define HIDN 2048
#define ROWST (BB * NN)   // 65536 token rows

using short8 = __attribute__((ext_vector_type(8))) short;   // 8 bf16 (4 VGPRs)
using f32x4  = __attribute__((ext_vector_type(4))) float;   // MFMA acc

__device__ __forceinline__ float bf2f(uint16_t h) {
  union { uint32_t u; float f; } v; v.u = ((uint32_t)h) << 16; return v.f;
}
__device__ __forceinline__ uint16_t f2bf(float f) {
  union { float f; uint32_t u; } v; v.f = f;
  return (uint16_t)((v.u + 0x7FFFu + ((v.u >> 16) & 1u)) >> 16);  // RNE
}
__device__ __forceinline__ float gelu_f(float x) {  // tanh-approx gelu (jax default)
  float u = 0.7978845608028654f * (x + 0.044715f * x * x * x);
  u = fminf(10.f, fmaxf(-10.f, u));
  float e = __expf(-2.f * u);
  float t = (1.f - e) / (1.f + e);
  return 0.5f * x * (1.f + t);
}
// async global->LDS, 16B/lane; LDS dest = wave-uniform base + lane*16
__device__ __forceinline__ void cp16(const uint16_t* g, uint16_t* l) {
  __builtin_amdgcn_global_load_lds((const __attribute__((address_space(1))) void*)g,
                                   (__attribute__((address_space(3))) void*)l, 16, 0, 0);
}
// XOR-swizzled LDS index for transposed [row][64] bf16 tiles: breaks the
// 8-way bank conflict on scattered u16 transpose-writes while keeping
// 8-element inner blocks contiguous for ds_read_b128.
__device__ __forceinline__ int swz(int row, int col) {
  return row * 64 + (col ^ (row & 56));
}

// ---------------- GEMM: C[M,N] = A[M,K](bf16) * B^T[N,K](bf16) + epilogue ----------------
// E: 0 phi->bf16, 1 +bias->bf16, 2 +bias+res->bf16, 3 gelu->bf16, 4 +bias+res->f32,
//    5 fused qkv: N=1536, cols 0-1023 phi, outputs split into 3 consecutive 64MiB buffers
template <int E>
__launch_bounds__(256)
__global__ void gemm_bt(const uint16_t* __restrict__ A, const uint16_t* __restrict__ BT,
                        const float* __restrict__ bias, const uint16_t* __restrict__ res,
                        void* __restrict__ outp, int M, int N, int K) {
  __shared__ __align__(16) uint16_t As[128 * 64];
  __shared__ __align__(16) uint16_t Bs[128 * 64];
  const int tid = threadIdx.x;
  const int lane = tid & 63, wave = tid >> 6;
  const int l15 = lane & 15, l4 = lane >> 4;
  const int m0 = blockIdx.x * 128, n0 = blockIdx.y * 128;
  const int wm = (wave >> 1) * 64, wn = (wave & 1) * 64;

  f32x4 acc[4][4];
#pragma unroll
  for (int i = 0; i < 4; ++i)
#pragma unroll
    for (int j = 0; j < 4; ++j) acc[i][j] = (f32x4){0.f, 0.f, 0.f, 0.f};

  const int srow = tid >> 3;        // 0..31: row within 32-row staging slice
  const int skc  = (tid & 7) * 8;   // k element offset within row
  const uint16_t* ga = A  + (size_t)(m0 + srow) * K + skc;
  const uint16_t* gb = BT + (size_t)(n0 + srow) * K + skc;

  for (int kb = 0; kb < K; kb += 64) {
    __syncthreads();                 // all waves done reading previous tile
#pragma unroll
    for (int i = 0; i < 4; ++i) {    // stage A(128x64) and B^T(128x64), 16B/lane
      cp16(ga + (size_t)i * 32 * K + kb, &As[(i * 256 + wave * 64) * 8]);
      cp16(gb + (size_t)i * 32 * K + kb, &Bs[(i * 256 + wave * 64) * 8]);
    }
    __syncthreads();                 // compiler drains vmcnt before barrier
#pragma unroll
    for (int kk = 0; kk < 64; kk += 32) {
      short8 af[4], bfr[4];
#pragma unroll
      for (int i = 0; i < 4; ++i)
        af[i] = *(const short8*)&As[(wm + i * 16 + l15) * 64 + kk + l4 * 8];
#pragma unroll
      for (int j = 0; j < 4; ++j)
        bfr[j] = *(const short8*)&Bs[(wn + j * 16 + l15) * 64 + kk + l4 * 8];
#pragma unroll
      for (int i = 0; i < 4; ++i)
#pragma unroll
        for (int j = 0; j < 4; ++j)
          acc[i][j] = __builtin_amdgcn_mfma_f32_16x16x32_bf16(af[i], bfr[j], acc[i][j], 0, 0, 0);
    }
  }

  uint16_t* outb = (uint16_t*)outp;
  float* outf = (float*)outp;
#pragma unroll
  for (int i = 0; i < 4; ++i)
#pragma unroll
    for (int r = 0; r < 4; ++r) {
      const int row = m0 + wm + i * 16 + l4 * 4 + r;   // C/D: row = quad*4+reg
#pragma unroll
      for (int j = 0; j < 4; ++j) {
        const int col = n0 + wn + j * 16 + l15;        // C/D: col = lane&15
        float v = acc[i][j][r] + bias[col];
        if (E == 5) {
          if (col < 1024) v = v > 0.f ? v + 1.f : __expf(v);
          outb[(size_t)(col >> 9) * ((size_t)ROWST * DD) + (size_t)row * DD + (col & 511)] = f2bf(v);
          continue;
        }
        const size_t idx = (size_t)row * N + col;
        if (E == 0)      { v = v > 0.f ? v + 1.f : __expf(v); outb[idx] = f2bf(v); }
        else if (E == 1) { outb[idx] = f2bf(v); }
        else if (E == 2) { v += bf2f(res[idx]); outb[idx] = f2bf(v); }
        else if (E == 3) { outb[idx] = f2bf(gelu_f(v)); }
        else             { v += bf2f(res[idx]); outf[idx] = v; }
      }
    }
}

// ---------------- LayerNorm: one wave per 512-elem row, out bf16 ----------------
template <int BFIN>
__launch_bounds__(256)
__global__ void ln_kernel(const void* __restrict__ inp, const float* __restrict__ gam,
                          const float* __restrict__ bet, uint16_t* __restrict__ out) {
  const int row = blockIdx.x * 4 + (threadIdx.x >> 6);
  const int lane = threadIdx.x & 63;
  const size_t base = (size_t)row * DD + lane * 8;
  float x[8];
  if (BFIN) {
    const uint4 u = *(const uint4*)((const uint16_t*)inp + base);
    x[0] = bf2f((uint16_t)(u.x & 0xffff)); x[1] = bf2f((uint16_t)(u.x >> 16));
    x[2] = bf2f((uint16_t)(u.y & 0xffff)); x[3] = bf2f((uint16_t)(u.y >> 16));
    x[4] = bf2f((uint16_t)(u.z & 0xffff)); x[5] = bf2f((uint16_t)(u.z >> 16));
    x[6] = bf2f((uint16_t)(u.w & 0xffff)); x[7] = bf2f((uint16_t)(u.w >> 16));
  } else {
    const float* f = (const float*)inp + base;
    const float4 a = *(const float4*)f;
    const float4 b = *(const float4*)(f + 4);
    x[0]=a.x; x[1]=a.y; x[2]=a.z; x[3]=a.w; x[4]=b.x; x[5]=b.y; x[6]=b.z; x[7]=b.w;
  }
  float s = 0.f, s2 = 0.f;
#pragma unroll
  for (int j = 0; j < 8; ++j) { s += x[j]; s2 += x[j] * x[j]; }
#pragma unroll
  for (int off = 32; off; off >>= 1) { s += __shfl_xor(s, off, 64); s2 += __shfl_xor(s2, off, 64); }
  const float m = s * (1.f / DD);
  const float rs = rsqrtf(s2 * (1.f / DD) - m * m + 1e-5f);
  uint16_t o[8];
#pragma unroll
  for (int j = 0; j < 8; ++j) {
    const int col = lane * 8 + j;
    o[j] = f2bf((x[j] - m) * rs * gam[col] + bet[col]);
  }
  uint4 w;
  w.x = (uint32_t)o[0] | ((uint32_t)o[1] << 16);
  w.y = (uint32_t)o[2] | ((uint32_t)o[3] << 16);
  w.z = (uint32_t)o[4] | ((uint32_t)o[5] << 16);
  w.w = (uint32_t)o[6] | ((uint32_t)o[7] << 16);
  *(uint4*)(out + base) = w;
}

// ---------------- weight transpose fp32[R,C] -> bf16[C,R] ----------------
__launch_bounds__(256)
__global__ void transpose_bf(const float* __restrict__ in, uint16_t* __restrict__ out,
                             int R, int C) {
  __shared__ float tile[32][33];
  const int tx = threadIdx.x, ty = threadIdx.y;
  const int c0 = blockIdx.x * 32, r0 = blockIdx.y * 32;
#pragma unroll
  for (int i = 0; i < 32; i += 8)
    tile[ty + i][tx] = in[(size_t)(r0 + ty + i) * C + (c0 + tx)];
  __syncthreads();
#pragma unroll
  for (int i = 0; i < 32; i += 8)
    out[(size_t)(c0 + ty + i) * R + (r0 + tx)] = f2bf(tile[tx][ty + i]);
}

__global__ void concat_bias(const float* __restrict__ bq, const float* __restrict__ bk,
                            const float* __restrict__ bv, float* __restrict__ o) {
  const int t = blockIdx.x * 256 + threadIdx.x;
  if (t < 512) o[t] = bq[t];
  else if (t < 1024) o[t] = bk[t - 512];
  else if (t < 1536) o[t] = bv[t - 1024];
}

// ---------------- kv partials via MFMA: kv[b,h,dk,dv] = sum_n pk*v ----------------
// grid (32 bh, 16 nchunk); 4 waves, each owns 256 rows in 4 transposed 64x64 LDS tiles.
// No barriers in the K-loop (wave-private tiles). Per-block partial -> ws.
__launch_bounds__(256)
__global__ void kv_mfma(const uint16_t* __restrict__ pk, const uint16_t* __restrict__ v,
                        float* __restrict__ kvp, float* __restrict__ ksp) {
  __shared__ __align__(16) uint16_t sT[4][2][64 * 64];  // [wave][pk|v][swizzled]
  __shared__ float ksred[64];
  const int bh = blockIdx.x, b = bh >> 3, h = bh & 7;
  const int t = threadIdx.x, lane = t & 63, w = t >> 6;
  const int l15 = lane & 15, l4 = lane >> 4;
  if (t < 64) ksred[t] = 0.f;
  __syncthreads();

  f32x4 acc[4][4];
#pragma unroll
  for (int i = 0; i < 4; ++i)
#pragma unroll
    for (int j = 0; j < 4; ++j) acc[i][j] = (f32x4){0.f, 0.f, 0.f, 0.f};
  float ks[4] = {0.f, 0.f, 0.f, 0.f};

  const int rl = lane >> 3, cl = (lane & 7) * 8;  // load: 8 rows x 64 cols per round
  for (int sc = 0; sc < 4; ++sc) {
    const int nbase = blockIdx.y * 1024 + w * 256 + sc * 64;
#pragma unroll
    for (int ro = 0; ro < 8; ++ro) {
      const int n = ro * 8 + rl;
      const size_t gofs = ((size_t)(b * NN + nbase + n) * HH + h) * 64 + cl;
      const short8 pv = *(const short8*)(pk + gofs);
      const short8 vv = *(const short8*)(v + gofs);
#pragma unroll
      for (int j = 0; j < 8; ++j) {           // transpose into [dk][n] / [dv][n]
        sT[w][0][swz(cl + j, n)] = (uint16_t)pv[j];
        sT[w][1][swz(cl + j, n)] = (uint16_t)vv[j];
      }
    }
#pragma unroll
    for (int kk = 0; kk < 64; kk += 32) {
      short8 af[4], bfr[4];
#pragma unroll
      for (int i = 0; i < 4; ++i)
        af[i] = *(const short8*)&sT[w][0][swz(i * 16 + l15, kk + l4 * 8)];
#pragma unroll
      for (int j = 0; j < 4; ++j)
        bfr[j] = *(const short8*)&sT[w][1][swz(j * 16 + l15, kk + l4 * 8)];
#pragma unroll
      for (int i = 0; i < 4; ++i) {
#pragma unroll
        for (int e = 0; e < 8; ++e) ks[i] += bf2f((uint16_t)af[i][e]);
#pragma unroll
        for (int j = 0; j < 4; ++j)
          acc[i][j] = __builtin_amdgcn_mfma_f32_16x16x32_bf16(af[i], bfr[j], acc[i][j], 0, 0, 0);
      }
    }
  }
  // ksum partial: reduce the 4 k-slices (quads) -> lane l4==0 holds dk=i*16+l15
#pragma unroll
  for (int i = 0; i < 4; ++i) {
    float s = ks[i];
    s += __shfl_xor(s, 16, 64); s += __shfl_xor(s, 32, 64);
    if (l4 == 0) atomicAdd(&ksred[i * 16 + l15], s);
  }
  __syncthreads();                       // everyone done with sT + ksred
  float* red = (float*)&sT[0][0][0];     // 48 KB scratch for waves 1..3
  if (w > 0) {
#pragma unroll
    for (int i = 0; i < 4; ++i)
#pragma unroll
      for (int r = 0; r < 4; ++r)
#pragma unroll
        for (int j = 0; j < 4; ++j)
          red[(w - 1) * 4096 + (i * 16 + l4 * 4 + r) * 64 + j * 16 + l15] = acc[i][j][r];
  }
  __syncthreads();
  if (w == 0) {
    float* dst = kvp + ((size_t)bh * 16 + blockIdx.y) * 4096;
#pragma unroll
    for (int i = 0; i < 4; ++i)
#pragma unroll
      for (int r = 0; r < 4; ++r)
#pragma unroll
        for (int j = 0; j < 4; ++j) {
          const int e = (i * 16 + l4 * 4 + r) * 64 + j * 16 + l15;
          dst[e] = acc[i][j][r] + red[e] + red[4096 + e] + red[8192 + e];
        }
  }
  if (t < 64) ksp[((size_t)bh * 16 + blockIdx.y) * 64 + t] = ksred[t];
}

// sum the 16 per-chunk partials. grid (32, 17): y==16 handles ksum.
__launch_bounds__(256)
__global__ void kv_reduce(const float* __restrict__ kvp, const float* __restrict__ ksp,
                          float* __restrict__ kv, float* __restrict__ ksum) {
  const int bh = blockIdx.x;
  if (blockIdx.y == 16) {
    if (threadIdx.x < 64) {
      float s = 0.f;
      for (int c = 0; c < 16; ++c) s += ksp[((size_t)bh * 16 + c) * 64 + threadIdx.x];
      ksum[bh * 64 + threadIdx.x] = s;
    }
    return;
  }
  const int e = blockIdx.y * 256 + threadIdx.x;
  float s = 0.f;
  for (int c = 0; c < 16; ++c) s += kvp[((size_t)bh * 16 + c) * 4096 + e];
  kv[(size_t)bh * 4096 + e] = s;
}

// ---------------- attn via MFMA: attn = (pq @ kv) / (pq . ksum + eps) ----------------
// grid (32 bh, 64); block 4 waves x 64 rows. A-frags direct from global (layout matches).
__launch_bounds__(256)
__global__ void attn_mfma(const uint16_t* __restrict__ pq, const float* __restrict__ kv,
                          const float* __restrict__ ksum, uint16_t* __restrict__ attn) {
  __shared__ __align__(16) uint16_t kvT[64 * 64];   // B: [dv][dk] swizzled, bf16
  __shared__ float ksS[64];
  __shared__ float denS[4][64];
  const int bh = blockIdx.x, b = bh >> 3, h = bh & 7;
  const int t = threadIdx.x, lane = t & 63, w = t >> 6;
  const int l15 = lane & 15, l4 = lane >> 4;
  const float* kvb = kv + (size_t)bh * 4096;
#pragma unroll
  for (int u = 0; u < 16; ++u) {
    const int e = u * 256 + t;                       // e = dk*64 + dv
    kvT[swz(e & 63, e >> 6)] = f2bf(kvb[e]);
  }
  if (t < 64) ksS[t] = ksum[bh * 64 + t];
  __syncthreads();

  float ksr[16];
#pragma unroll
  for (int kk2 = 0; kk2 < 2; ++kk2) {
    const float4 k0 = *(const float4*)&ksS[kk2 * 32 + l4 * 8];
    const float4 k1 = *(const float4*)&ksS[kk2 * 32 + l4 * 8 + 4];
    ksr[kk2 * 8 + 0] = k0.x; ksr[kk2 * 8 + 1] = k0.y; ksr[kk2 * 8 + 2] = k0.z; ksr[kk2 * 8 + 3] = k0.w;
    ksr[kk2 * 8 + 4] = k1.x; ksr[kk2 * 8 + 5] = k1.y; ksr[kk2 * 8 + 6] = k1.z; ksr[kk2 * 8 + 7] = k1.w;
  }
  short8 bfrg[2][4];
#pragma unroll
  for (int kk2 = 0; kk2 < 2; ++kk2)
#pragma unroll
    for (int j = 0; j < 4; ++j)
      bfrg[kk2][j] = *(const short8*)&kvT[swz(j * 16 + l15, kk2 * 32 + l4 * 8)];

  const int n0w = blockIdx.y * 256 + w * 64;
  f32x4 acc[4][4];
#pragma unroll
  for (int i = 0; i < 4; ++i)
#pragma unroll
    for (int j = 0; j < 4; ++j) acc[i][j] = (f32x4){0.f, 0.f, 0.f, 0.f};
  float den[4] = {0.f, 0.f, 0.f, 0.f};

#pragma unroll
  for (int i = 0; i < 4; ++i) {
    const int n = n0w + i * 16 + l15;
    const size_t abase = ((size_t)(b * NN + n) * HH + h) * 64 + l4 * 8;
#pragma unroll
    for (int kk2 = 0; kk2 < 2; ++kk2) {
      const short8 af = *(const short8*)(pq + abase + kk2 * 32);
#pragma unroll
      for (int e = 0; e < 8; ++e) den[i] += bf2f((uint16_t)af[e]) * ksr[kk2 * 8 + e];
#pragma unroll
      for (int j = 0; j < 4; ++j)
        acc[i][j] = __builtin_amdgcn_mfma_f32_16x16x32_bf16(af, bfrg[kk2][j], acc[i][j], 0, 0, 0);
    }
  }
#pragma unroll
  for (int i = 0; i < 4; ++i) {
    float s = den[i];
    s += __shfl_xor(s, 16, 64); s += __shfl_xor(s, 32, 64);
    if (l4 == 0) denS[w][i * 16 + l15] = s;          // same-wave LDS, in-order
  }
#pragma unroll
  for (int i = 0; i < 4; ++i)
#pragma unroll
    for (int r = 0; r < 4; ++r) {
      const float z = 1.f / (denS[w][i * 16 + l4 * 4 + r] + 1e-6f);
      const int n = n0w + i * 16 + l4 * 4 + r;
      const size_t ob = ((size_t)(b * NN + n) * HH + h) * 64;
#pragma unroll
      for (int j = 0; j < 4; ++j)
        attn[ob + j * 16 + l15] = f2bf(acc[i][j][r] * z);
    }
}

// ---------------- host launch ----------------
extern "C" void kernel_launch(void* const* d_in, const int* in_sizes, int n_in,
                              void* d_out, int out_size, void* d_ws, size_t ws_size,
                              hipStream_t stream) {
  (void)in_sizes; (void)n_in; (void)out_size;
  const float* x    = (const float*)d_in[0];
  const float* ln1g = (const float*)d_in[1];
  const float* ln1b = (const float*)d_in[2];
  const float* Wq   = (const float*)d_in[3];
  const float* bq   = (const float*)d_in[4];
  const float* Wk   = (const float*)d_in[5];
  const float* bk   = (const float*)d_in[6];
  const float* Wv   = (const float*)d_in[7];
  const float* bv   = (const float*)d_in[8];
  const float* Wo   = (const float*)d_in[9];
  const float* bo   = (const float*)d_in[10];
  const float* ln2g = (const float*)d_in[11];
  const float* ln2b = (const float*)d_in[12];
  const float* W1   = (const float*)d_in[13];
  const float* b1   = (const float*)d_in[14];
  const float* W2   = (const float*)d_in[15];
  const float* b2   = (const float*)d_in[16];

  if (ws_size < 409000000ULL) return;

  char* p = (char*)d_ws;
  auto alloc = [&](size_t bytes) -> char* {
    char* r = p; p += (bytes + 255) & ~(size_t)255; return r;
  };
  uint16_t* Hb  = (uint16_t*)alloc((size_t)ROWST * DD * 2);   // h (LN1 out)
  uint16_t* PQ  = (uint16_t*)alloc((size_t)ROWST * DD * 2);   // phi(q); later h2
  uint16_t* PK  = (uint16_t*)alloc((size_t)ROWST * DD * 2);   // phi(k); later hres  (contig after PQ)
  uint16_t* PV  = (uint16_t*)alloc((size_t)ROWST * DD * 2);   // v; later attn      (contig after PK)
  uint16_t* U   = (uint16_t*)alloc((size_t)32768 * HIDN * 2); // MLP hidden chunk (also hosts kv scratch)
  uint16_t* WqkvT = (uint16_t*)alloc((size_t)1536 * DD * 2);
  uint16_t* WoT = (uint16_t*)alloc((size_t)DD * DD * 2);
  uint16_t* W1T = (uint16_t*)alloc((size_t)HIDN * DD * 2);
  uint16_t* W2T = (uint16_t*)alloc((size_t)DD * HIDN * 2);
  float*    bqkv = (float*)alloc(1536 * 4);
  // kv scratch lives inside U (used before the MLP phase touches U)
  float* KVP = (float*)U;                  // 512*4096 fp32 = 8 MiB
  float* KSP = KVP + 512 * 4096;           // 512*64 fp32
  float* KV  = KSP + 512 * 64;             // 32*4096 fp32
  float* KS  = KV + 32 * 4096;             // 32*64 fp32

  const dim3 tb(32, 8);
  transpose_bf<<<dim3(16, 16), tb, 0, stream>>>(Wq, WqkvT, DD, DD);
  transpose_bf<<<dim3(16, 16), tb, 0, stream>>>(Wk, WqkvT + 512 * 512, DD, DD);
  transpose_bf<<<dim3(16, 16), tb, 0, stream>>>(Wv, WqkvT + 2 * 512 * 512, DD, DD);
  transpose_bf<<<dim3(16, 16), tb, 0, stream>>>(Wo, WoT, DD, DD);
  transpose_bf<<<dim3(64, 16), tb, 0, stream>>>(W1, W1T, DD, HIDN);
  transpose_bf<<<dim3(16, 64), tb, 0, stream>>>(W2, W2T, HIDN, DD);
  concat_bias<<<6, 256, 0, stream>>>(bq, bk, bv, bqkv);

  // h = LN1(x)
  ln_kernel<0><<<ROWST / 4, 256, 0, stream>>>(x, ln1g, ln1b, Hb);
  // fused qkv: [pq|pk|v] = epi(h @ Wqkv + b)
  gemm_bt<5><<<dim3(512, 12), 256, 0, stream>>>(Hb, WqkvT, bqkv, nullptr, PQ, ROWST, 1536, DD);
  // kv / ksum via MFMA partials + reduce
  kv_mfma<<<dim3(32, 16), 256, 0, stream>>>(PK, PV, KVP, KSP);
  kv_reduce<<<dim3(32, 17), 256, 0, stream>>>(KVP, KSP, KV, KS);
  // attn (normalized) -> PV
  attn_mfma<<<dim3(32, 64), 256, 0, stream>>>(PQ, KV, KS, PV);
  // hres = attn@Wo + bo + h -> PK
  gemm_bt<2><<<dim3(512, 4), 256, 0, stream>>>(PV, WoT, bo, Hb, PK, ROWST, DD, DD);
  // h2 = LN2(hres) -> PQ
  ln_kernel<1><<<ROWST / 4, 256, 0, stream>>>(PK, ln2g, ln2b, PQ);
  // MLP in 2 row-chunks: out = h2 + gelu(h2@W1+b1)@W2 + b2
  for (int c = 0; c < 2; ++c) {
    const uint16_t* h2c = PQ + (size_t)c * 32768 * DD;
    gemm_bt<3><<<dim3(256, 16), 256, 0, stream>>>(h2c, W1T, b1, nullptr, U, 32768, HIDN, DD);
    gemm_bt<4><<<dim3(256, 4), 256, 0, stream>>>(U, W2T, b2, h2c,
        (float*)d_out + (size_t)c * 32768 * DD, 32768, DD, HIDN);
  }
}

// Round 3
// 1141.660 us; speedup vs baseline: 1.3293x; 1.0541x over previous
//
#include <hip/hip_runtime.h>
#include <stdint.h>

// Problem constants
#define BB   4
#define NN   16384
#define HH   8
#define DD   512
#define HIDN 2048
#define ROWST (BB * NN)   // 65536 token rows

using short8 = __attribute__((ext_vector_type(8))) short;   // 8 bf16 (4 VGPRs)
using f32x4  = __attribute__((ext_vector_type(4))) float;   // MFMA acc

__device__ __forceinline__ float bf2f(uint16_t h) {
  union { uint32_t u; float f; } v; v.u = ((uint32_t)h) << 16; return v.f;
}
__device__ __forceinline__ uint16_t f2bf(float f) {
  union { float f; uint32_t u; } v; v.f = f;
  return (uint16_t)((v.u + 0x7FFFu + ((v.u >> 16) & 1u)) >> 16);  // RNE
}
__device__ __forceinline__ float gelu_f(float x) {  // tanh-approx gelu (jax default)
  float u = 0.7978845608028654f * (x + 0.044715f * x * x * x);
  u = fminf(10.f, fmaxf(-10.f, u));
  float e = __expf(-2.f * u);
  float t = (1.f - e) / (1.f + e);
  return 0.5f * x * (1.f + t);
}
// async global->LDS, 16B/lane; LDS dest = wave-uniform base + lane*16
__device__ __forceinline__ void cp16(const uint16_t* g, uint16_t* l) {
  __builtin_amdgcn_global_load_lds((const __attribute__((address_space(1))) void*)g,
                                   (__attribute__((address_space(3))) void*)l, 16, 0, 0);
}
// XOR-swizzled LDS index for transposed [row][64] bf16 tiles (kv/attn kernels).
__device__ __forceinline__ int swz(int row, int col) {
  return row * 64 + (col ^ (row & 56));
}

// ---------------- GEMM: C[M,N] = A[M,K](bf16) * B^T[N,K](bf16) + epilogue ----------------
// Grid: blockIdx.x = n-tile (FAST — keeps A-stripe in L2 across n-sweep),
//       blockIdx.y = m-tile.
// LDS tiles are XOR-swizzled by (row&7) on the 16B col-block, applied at the
// global source address during global_load_lds staging (bank-conflict fix:
// 16-way -> 2-way on ds_read_b128).
// E: 0 phi->bf16, 1 +bias->bf16, 2 +bias+res->bf16, 3 gelu->bf16, 4 +bias+res->f32,
//    5 fused qkv: N=1536, cols 0-1023 phi, outputs split into 3 consecutive buffers
template <int E>
__launch_bounds__(256)
__global__ void gemm_bt(const uint16_t* __restrict__ A, const uint16_t* __restrict__ BT,
                        const float* __restrict__ bias, const uint16_t* __restrict__ res,
                        void* __restrict__ outp, int M, int N, int K) {
  __shared__ __align__(16) uint16_t As[128 * 64];
  __shared__ __align__(16) uint16_t Bs[128 * 64];
  const int tid = threadIdx.x;
  const int lane = tid & 63, wave = tid >> 6;
  const int l15 = lane & 15, l4 = lane >> 4;
  const int m0 = blockIdx.y * 128, n0 = blockIdx.x * 128;
  const int wm = (wave >> 1) * 64, wn = (wave & 1) * 64;

  f32x4 acc[4][4];
#pragma unroll
  for (int i = 0; i < 4; ++i)
#pragma unroll
    for (int j = 0; j < 4; ++j) acc[i][j] = (f32x4){0.f, 0.f, 0.f, 0.f};

  const int srow = tid >> 3;                    // 0..31: row within 32-row slice
  const int skc  = ((tid & 7) ^ (srow & 7)) * 8;  // swizzled source col-block
  const uint16_t* ga = A  + (size_t)(m0 + srow) * K + skc;
  const uint16_t* gb = BT + (size_t)(n0 + srow) * K + skc;

  for (int kb = 0; kb < K; kb += 64) {
    __syncthreads();                 // all waves done reading previous tile
#pragma unroll
    for (int i = 0; i < 4; ++i) {    // stage A(128x64) and B^T(128x64), 16B/lane
      cp16(ga + (size_t)i * 32 * K + kb, &As[(i * 256 + wave * 64) * 8]);
      cp16(gb + (size_t)i * 32 * K + kb, &Bs[(i * 256 + wave * 64) * 8]);
    }
    __syncthreads();                 // compiler drains vmcnt before barrier
#pragma unroll
    for (int kk = 0; kk < 64; kk += 32) {
      short8 af[4], bfr[4];
#pragma unroll
      for (int i = 0; i < 4; ++i)
        af[i] = *(const short8*)&As[(wm + i * 16 + l15) * 64 +
                                    ((((kk >> 3) + l4) ^ (l15 & 7)) * 8)];
#pragma unroll
      for (int j = 0; j < 4; ++j)
        bfr[j] = *(const short8*)&Bs[(wn + j * 16 + l15) * 64 +
                                     ((((kk >> 3) + l4) ^ (l15 & 7)) * 8)];
#pragma unroll
      for (int i = 0; i < 4; ++i)
#pragma unroll
        for (int j = 0; j < 4; ++j)
          acc[i][j] = __builtin_amdgcn_mfma_f32_16x16x32_bf16(af[i], bfr[j], acc[i][j], 0, 0, 0);
    }
  }

  uint16_t* outb = (uint16_t*)outp;
  float* outf = (float*)outp;
#pragma unroll
  for (int i = 0; i < 4; ++i)
#pragma unroll
    for (int r = 0; r < 4; ++r) {
      const int row = m0 + wm + i * 16 + l4 * 4 + r;   // C/D: row = quad*4+reg
#pragma unroll
      for (int j = 0; j < 4; ++j) {
        const int col = n0 + wn + j * 16 + l15;        // C/D: col = lane&15
        float v = acc[i][j][r] + bias[col];
        if (E == 5) {
          if (col < 1024) v = v > 0.f ? v + 1.f : __expf(v);
          outb[(size_t)(col >> 9) * ((size_t)ROWST * DD) + (size_t)row * DD + (col & 511)] = f2bf(v);
          continue;
        }
        const size_t idx = (size_t)row * N + col;
        if (E == 0)      { v = v > 0.f ? v + 1.f : __expf(v); outb[idx] = f2bf(v); }
        else if (E == 1) { outb[idx] = f2bf(v); }
        else if (E == 2) { v += bf2f(res[idx]); outb[idx] = f2bf(v); }
        else if (E == 3) { outb[idx] = f2bf(gelu_f(v)); }
        else             { v += bf2f(res[idx]); outf[idx] = v; }
      }
    }
}

// ---------------- LayerNorm: one wave per 512-elem row, out bf16 ----------------
template <int BFIN>
__launch_bounds__(256)
__global__ void ln_kernel(const void* __restrict__ inp, const float* __restrict__ gam,
                          const float* __restrict__ bet, uint16_t* __restrict__ out) {
  const int row = blockIdx.x * 4 + (threadIdx.x >> 6);
  const int lane = threadIdx.x & 63;
  const size_t base = (size_t)row * DD + lane * 8;
  float x[8];
  if (BFIN) {
    const uint4 u = *(const uint4*)((const uint16_t*)inp + base);
    x[0] = bf2f((uint16_t)(u.x & 0xffff)); x[1] = bf2f((uint16_t)(u.x >> 16));
    x[2] = bf2f((uint16_t)(u.y & 0xffff)); x[3] = bf2f((uint16_t)(u.y >> 16));
    x[4] = bf2f((uint16_t)(u.z & 0xffff)); x[5] = bf2f((uint16_t)(u.z >> 16));
    x[6] = bf2f((uint16_t)(u.w & 0xffff)); x[7] = bf2f((uint16_t)(u.w >> 16));
  } else {
    const float* f = (const float*)inp + base;
    const float4 a = *(const float4*)f;
    const float4 b = *(const float4*)(f + 4);
    x[0]=a.x; x[1]=a.y; x[2]=a.z; x[3]=a.w; x[4]=b.x; x[5]=b.y; x[6]=b.z; x[7]=b.w;
  }
  float s = 0.f, s2 = 0.f;
#pragma unroll
  for (int j = 0; j < 8; ++j) { s += x[j]; s2 += x[j] * x[j]; }
#pragma unroll
  for (int off = 32; off; off >>= 1) { s += __shfl_xor(s, off, 64); s2 += __shfl_xor(s2, off, 64); }
  const float m = s * (1.f / DD);
  const float rs = rsqrtf(s2 * (1.f / DD) - m * m + 1e-5f);
  uint16_t o[8];
#pragma unroll
  for (int j = 0; j < 8; ++j) {
    const int col = lane * 8 + j;
    o[j] = f2bf((x[j] - m) * rs * gam[col] + bet[col]);
  }
  uint4 w;
  w.x = (uint32_t)o[0] | ((uint32_t)o[1] << 16);
  w.y = (uint32_t)o[2] | ((uint32_t)o[3] << 16);
  w.z = (uint32_t)o[4] | ((uint32_t)o[5] << 16);
  w.w = (uint32_t)o[6] | ((uint32_t)o[7] << 16);
  *(uint4*)(out + base) = w;
}

// ---------------- weight transpose fp32[R,C] -> bf16[C,R] ----------------
__launch_bounds__(256)
__global__ void transpose_bf(const float* __restrict__ in, uint16_t* __restrict__ out,
                             int R, int C) {
  __shared__ float tile[32][33];
  const int tx = threadIdx.x, ty = threadIdx.y;
  const int c0 = blockIdx.x * 32, r0 = blockIdx.y * 32;
#pragma unroll
  for (int i = 0; i < 32; i += 8)
    tile[ty + i][tx] = in[(size_t)(r0 + ty + i) * C + (c0 + tx)];
  __syncthreads();
#pragma unroll
  for (int i = 0; i < 32; i += 8)
    out[(size_t)(c0 + ty + i) * R + (r0 + tx)] = f2bf(tile[tx][ty + i]);
}

__global__ void concat_bias(const float* __restrict__ bq, const float* __restrict__ bk,
                            const float* __restrict__ bv, float* __restrict__ o) {
  const int t = blockIdx.x * 256 + threadIdx.x;
  if (t < 512) o[t] = bq[t];
  else if (t < 1024) o[t] = bk[t - 512];
  else if (t < 1536) o[t] = bv[t - 1024];
}

// ---------------- kv partials via MFMA: kv[b,h,dk,dv] = sum_n pk*v ----------------
// grid (32 bh, 16 nchunk); 4 waves, each owns 256 rows in 4 transposed 64x64 LDS tiles.
// No barriers in the K-loop (wave-private tiles). Per-block partial -> ws.
__launch_bounds__(256)
__global__ void kv_mfma(const uint16_t* __restrict__ pk, const uint16_t* __restrict__ v,
                        float* __restrict__ kvp, float* __restrict__ ksp) {
  __shared__ __align__(16) uint16_t sT[4][2][64 * 64];  // [wave][pk|v][swizzled]
  __shared__ float ksred[64];
  const int bh = blockIdx.x, b = bh >> 3, h = bh & 7;
  const int t = threadIdx.x, lane = t & 63, w = t >> 6;
  const int l15 = lane & 15, l4 = lane >> 4;
  if (t < 64) ksred[t] = 0.f;
  __syncthreads();

  f32x4 acc[4][4];
#pragma unroll
  for (int i = 0; i < 4; ++i)
#pragma unroll
    for (int j = 0; j < 4; ++j) acc[i][j] = (f32x4){0.f, 0.f, 0.f, 0.f};
  float ks[4] = {0.f, 0.f, 0.f, 0.f};

  const int rl = lane >> 3, cl = (lane & 7) * 8;  // load: 8 rows x 64 cols per round
  for (int sc = 0; sc < 4; ++sc) {
    const int nbase = blockIdx.y * 1024 + w * 256 + sc * 64;
#pragma unroll
    for (int ro = 0; ro < 8; ++ro) {
      const int n = ro * 8 + rl;
      const size_t gofs = ((size_t)(b * NN + nbase + n) * HH + h) * 64 + cl;
      const short8 pv = *(const short8*)(pk + gofs);
      const short8 vv = *(const short8*)(v + gofs);
#pragma unroll
      for (int j = 0; j < 8; ++j) {           // transpose into [dk][n] / [dv][n]
        sT[w][0][swz(cl + j, n)] = (uint16_t)pv[j];
        sT[w][1][swz(cl + j, n)] = (uint16_t)vv[j];
      }
    }
#pragma unroll
    for (int kk = 0; kk < 64; kk += 32) {
      short8 af[4], bfr[4];
#pragma unroll
      for (int i = 0; i < 4; ++i)
        af[i] = *(const short8*)&sT[w][0][swz(i * 16 + l15, kk + l4 * 8)];
#pragma unroll
      for (int j = 0; j < 4; ++j)
        bfr[j] = *(const short8*)&sT[w][1][swz(j * 16 + l15, kk + l4 * 8)];
#pragma unroll
      for (int i = 0; i < 4; ++i) {
#pragma unroll
        for (int e = 0; e < 8; ++e) ks[i] += bf2f((uint16_t)af[i][e]);
#pragma unroll
        for (int j = 0; j < 4; ++j)
          acc[i][j] = __builtin_amdgcn_mfma_f32_16x16x32_bf16(af[i], bfr[j], acc[i][j], 0, 0, 0);
      }
    }
  }
  // ksum partial: reduce the 4 k-slices (quads) -> lane l4==0 holds dk=i*16+l15
#pragma unroll
  for (int i = 0; i < 4; ++i) {
    float s = ks[i];
    s += __shfl_xor(s, 16, 64); s += __shfl_xor(s, 32, 64);
    if (l4 == 0) atomicAdd(&ksred[i * 16 + l15], s);
  }
  __syncthreads();                       // everyone done with sT + ksred
  float* red = (float*)&sT[0][0][0];     // 48 KB scratch for waves 1..3
  if (w > 0) {
#pragma unroll
    for (int i = 0; i < 4; ++i)
#pragma unroll
      for (int r = 0; r < 4; ++r)
#pragma unroll
        for (int j = 0; j < 4; ++j)
          red[(w - 1) * 4096 + (i * 16 + l4 * 4 + r) * 64 + j * 16 + l15] = acc[i][j][r];
  }
  __syncthreads();
  if (w == 0) {
    float* dst = kvp + ((size_t)bh * 16 + blockIdx.y) * 4096;
#pragma unroll
    for (int i = 0; i < 4; ++i)
#pragma unroll
      for (int r = 0; r < 4; ++r)
#pragma unroll
        for (int j = 0; j < 4; ++j) {
          const int e = (i * 16 + l4 * 4 + r) * 64 + j * 16 + l15;
          dst[e] = acc[i][j][r] + red[e] + red[4096 + e] + red[8192 + e];
        }
  }
  if (t < 64) ksp[((size_t)bh * 16 + blockIdx.y) * 64 + t] = ksred[t];
}

// sum the 16 per-chunk partials. grid (32, 17): y==16 handles ksum.
__launch_bounds__(256)
__global__ void kv_reduce(const float* __restrict__ kvp, const float* __restrict__ ksp,
                          float* __restrict__ kv, float* __restrict__ ksum) {
  const int bh = blockIdx.x;
  if (blockIdx.y == 16) {
    if (threadIdx.x < 64) {
      float s = 0.f;
      for (int c = 0; c < 16; ++c) s += ksp[((size_t)bh * 16 + c) * 64 + threadIdx.x];
      ksum[bh * 64 + threadIdx.x] = s;
    }
    return;
  }
  const int e = blockIdx.y * 256 + threadIdx.x;
  float s = 0.f;
  for (int c = 0; c < 16; ++c) s += kvp[((size_t)bh * 16 + c) * 4096 + e];
  kv[(size_t)bh * 4096 + e] = s;
}

// ---------------- attn via MFMA: attn = (pq @ kv) / (pq . ksum + eps) ----------------
// grid (32 bh, 64); block 4 waves x 64 rows. A-frags direct from global (layout matches).
__launch_bounds__(256)
__global__ void attn_mfma(const uint16_t* __restrict__ pq, const float* __restrict__ kv,
                          const float* __restrict__ ksum, uint16_t* __restrict__ attn) {
  __shared__ __align__(16) uint16_t kvT[64 * 64];   // B: [dv][dk] swizzled, bf16
  __shared__ float ksS[64];
  __shared__ float denS[4][64];
  const int bh = blockIdx.x, b = bh >> 3, h = bh & 7;
  const int t = threadIdx.x, lane = t & 63, w = t >> 6;
  const int l15 = lane & 15, l4 = lane >> 4;
  const float* kvb = kv + (size_t)bh * 4096;
#pragma unroll
  for (int u = 0; u < 16; ++u) {
    const int e = u * 256 + t;                       // e = dk*64 + dv
    kvT[swz(e & 63, e >> 6)] = f2bf(kvb[e]);
  }
  if (t < 64) ksS[t] = ksum[bh * 64 + t];
  __syncthreads();

  float ksr[16];
#pragma unroll
  for (int kk2 = 0; kk2 < 2; ++kk2) {
    const float4 k0 = *(const float4*)&ksS[kk2 * 32 + l4 * 8];
    const float4 k1 = *(const float4*)&ksS[kk2 * 32 + l4 * 8 + 4];
    ksr[kk2 * 8 + 0] = k0.x; ksr[kk2 * 8 + 1] = k0.y; ksr[kk2 * 8 + 2] = k0.z; ksr[kk2 * 8 + 3] = k0.w;
    ksr[kk2 * 8 + 4] = k1.x; ksr[kk2 * 8 + 5] = k1.y; ksr[kk2 * 8 + 6] = k1.z; ksr[kk2 * 8 + 7] = k1.w;
  }
  short8 bfrg[2][4];
#pragma unroll
  for (int kk2 = 0; kk2 < 2; ++kk2)
#pragma unroll
    for (int j = 0; j < 4; ++j)
      bfrg[kk2][j] = *(const short8*)&kvT[swz(j * 16 + l15, kk2 * 32 + l4 * 8)];

  const int n0w = blockIdx.y * 256 + w * 64;
  f32x4 acc[4][4];
#pragma unroll
  for (int i = 0; i < 4; ++i)
#pragma unroll
    for (int j = 0; j < 4; ++j) acc[i][j] = (f32x4){0.f, 0.f, 0.f, 0.f};
  float den[4] = {0.f, 0.f, 0.f, 0.f};

#pragma unroll
  for (int i = 0; i < 4; ++i) {
    const int n = n0w + i * 16 + l15;
    const size_t abase = ((size_t)(b * NN + n) * HH + h) * 64 + l4 * 8;
#pragma unroll
    for (int kk2 = 0; kk2 < 2; ++kk2) {
      const short8 af = *(const short8*)(pq + abase + kk2 * 32);
#pragma unroll
      for (int e = 0; e < 8; ++e) den[i] += bf2f((uint16_t)af[e]) * ksr[kk2 * 8 + e];
#pragma unroll
      for (int j = 0; j < 4; ++j)
        acc[i][j] = __builtin_amdgcn_mfma_f32_16x16x32_bf16(af, bfrg[kk2][j], acc[i][j], 0, 0, 0);
    }
  }
#pragma unroll
  for (int i = 0; i < 4; ++i) {
    float s = den[i];
    s += __shfl_xor(s, 16, 64); s += __shfl_xor(s, 32, 64);
    if (l4 == 0) denS[w][i * 16 + l15] = s;          // same-wave LDS, in-order
  }
#pragma unroll
  for (int i = 0; i < 4; ++i)
#pragma unroll
    for (int r = 0; r < 4; ++r) {
      const float z = 1.f / (denS[w][i * 16 + l4 * 4 + r] + 1e-6f);
      const int n = n0w + i * 16 + l4 * 4 + r;
      const size_t ob = ((size_t)(b * NN + n) * HH + h) * 64;
#pragma unroll
      for (int j = 0; j < 4; ++j)
        attn[ob + j * 16 + l15] = f2bf(acc[i][j][r] * z);
    }
}

// ---------------- host launch ----------------
extern "C" void kernel_launch(void* const* d_in, const int* in_sizes, int n_in,
                              void* d_out, int out_size, void* d_ws, size_t ws_size,
                              hipStream_t stream) {
  (void)in_sizes; (void)n_in; (void)out_size;
  const float* x    = (const float*)d_in[0];
  const float* ln1g = (const float*)d_in[1];
  const float* ln1b = (const float*)d_in[2];
  const float* Wq   = (const float*)d_in[3];
  const float* bq   = (const float*)d_in[4];
  const float* Wk   = (const float*)d_in[5];
  const float* bk   = (const float*)d_in[6];
  const float* Wv   = (const float*)d_in[7];
  const float* bv   = (const float*)d_in[8];
  const float* Wo   = (const float*)d_in[9];
  const float* bo   = (const float*)d_in[10];
  const float* ln2g = (const float*)d_in[11];
  const float* ln2b = (const float*)d_in[12];
  const float* W1   = (const float*)d_in[13];
  const float* b1   = (const float*)d_in[14];
  const float* W2   = (const float*)d_in[15];
  const float* b2   = (const float*)d_in[16];

  if (ws_size < 409000000ULL) return;

  char* p = (char*)d_ws;
  auto alloc = [&](size_t bytes) -> char* {
    char* r = p; p += (bytes + 255) & ~(size_t)255; return r;
  };
  uint16_t* Hb  = (uint16_t*)alloc((size_t)ROWST * DD * 2);   // h (LN1 out)
  uint16_t* PQ  = (uint16_t*)alloc((size_t)ROWST * DD * 2);   // phi(q); later h2
  uint16_t* PK  = (uint16_t*)alloc((size_t)ROWST * DD * 2);   // phi(k); later hres  (contig after PQ)
  uint16_t* PV  = (uint16_t*)alloc((size_t)ROWST * DD * 2);   // v; later attn      (contig after PK)
  uint16_t* U   = (uint16_t*)alloc((size_t)32768 * HIDN * 2); // MLP hidden chunk (also hosts kv scratch)
  uint16_t* WqkvT = (uint16_t*)alloc((size_t)1536 * DD * 2);
  uint16_t* WoT = (uint16_t*)alloc((size_t)DD * DD * 2);
  uint16_t* W1T = (uint16_t*)alloc((size_t)HIDN * DD * 2);
  uint16_t* W2T = (uint16_t*)alloc((size_t)DD * HIDN * 2);
  float*    bqkv = (float*)alloc(1536 * 4);
  // kv scratch lives inside U (used before the MLP phase touches U)
  float* KVP = (float*)U;                  // 512*4096 fp32 = 8 MiB
  float* KSP = KVP + 512 * 4096;           // 512*64 fp32
  float* KV  = KSP + 512 * 64;             // 32*4096 fp32
  float* KS  = KV + 32 * 4096;             // 32*64 fp32

  const dim3 tb(32, 8);
  transpose_bf<<<dim3(16, 16), tb, 0, stream>>>(Wq, WqkvT, DD, DD);
  transpose_bf<<<dim3(16, 16), tb, 0, stream>>>(Wk, WqkvT + 512 * 512, DD, DD);
  transpose_bf<<<dim3(16, 16), tb, 0, stream>>>(Wv, WqkvT + 2 * 512 * 512, DD, DD);
  transpose_bf<<<dim3(16, 16), tb, 0, stream>>>(Wo, WoT, DD, DD);
  transpose_bf<<<dim3(64, 16), tb, 0, stream>>>(W1, W1T, DD, HIDN);
  transpose_bf<<<dim3(16, 64), tb, 0, stream>>>(W2, W2T, HIDN, DD);
  concat_bias<<<6, 256, 0, stream>>>(bq, bk, bv, bqkv);

  // h = LN1(x)
  ln_kernel<0><<<ROWST / 4, 256, 0, stream>>>(x, ln1g, ln1b, Hb);
  // fused qkv: [pq|pk|v] = epi(h @ Wqkv + b)   (n-tiles fastest)
  gemm_bt<5><<<dim3(12, 512), 256, 0, stream>>>(Hb, WqkvT, bqkv, nullptr, PQ, ROWST, 1536, DD);
  // kv / ksum via MFMA partials + reduce
  kv_mfma<<<dim3(32, 16), 256, 0, stream>>>(PK, PV, KVP, KSP);
  kv_reduce<<<dim3(32, 17), 256, 0, stream>>>(KVP, KSP, KV, KS);
  // attn (normalized) -> PV
  attn_mfma<<<dim3(32, 64), 256, 0, stream>>>(PQ, KV, KS, PV);
  // hres = attn@Wo + bo + h -> PK
  gemm_bt<2><<<dim3(4, 512), 256, 0, stream>>>(PV, WoT, bo, Hb, PK, ROWST, DD, DD);
  // h2 = LN2(hres) -> PQ
  ln_kernel<1><<<ROWST / 4, 256, 0, stream>>>(PK, ln2g, ln2b, PQ);
  // MLP in 2 row-chunks: out = h2 + gelu(h2@W1+b1)@W2 + b2
  for (int c = 0; c < 2; ++c) {
    const uint16_t* h2c = PQ + (size_t)c * 32768 * DD;
    gemm_bt<3><<<dim3(16, 256), 256, 0, stream>>>(h2c, W1T, b1, nullptr, U, 32768, HIDN, DD);
    gemm_bt<4><<<dim3(4, 256), 256, 0, stream>>>(U, W2T, b2, h2c,
        (float*)d_out + (size_t)c * 32768 * DD, 32768, DD, HIDN);
  }
}

// Round 4
// 1037.531 us; speedup vs baseline: 1.4627x; 1.1004x over previous
//
#include <hip/hip_runtime.h>
#include <stdint.h>

// Problem constants
#define BB   4
#define NN   16384
#define HH   8
#define DD   512
#define HIDN 2048
#define ROWST (BB * NN)   // 65536 token rows

using short8 = __attribute__((ext_vector_type(8))) short;   // 8 bf16 (4 VGPRs)
using f32x4  = __attribute__((ext_vector_type(4))) float;   // MFMA acc

__device__ __forceinline__ float bf2f(uint16_t h) {
  union { uint32_t u; float f; } v; v.u = ((uint32_t)h) << 16; return v.f;
}
__device__ __forceinline__ uint16_t f2bf(float f) {
  union { float f; uint32_t u; } v; v.f = f;
  return (uint16_t)((v.u + 0x7FFFu + ((v.u >> 16) & 1u)) >> 16);  // RNE
}
// gelu tanh-approx via sigmoid identity: 0.5x(1+tanh(u)) == x*sigmoid(2u).
// 8 VALU ops, one v_exp_f32 + one v_rcp_f32, saturates correctly at +-inf.
__device__ __forceinline__ float gelu_f(float x) {
  const float t1 = x * x;
  const float inner = __builtin_fmaf(0.044715f * t1, x, x);  // x + 0.044715x^3
  const float e = __expf(-1.5957691216f * inner);            // exp(-2u)
  return x * __builtin_amdgcn_rcpf(1.f + e);
}
// async global->LDS, 16B/lane; LDS dest = wave-uniform base + lane*16
__device__ __forceinline__ void cp16(const uint16_t* g, uint16_t* l) {
  __builtin_amdgcn_global_load_lds((const __attribute__((address_space(1))) void*)g,
                                   (__attribute__((address_space(3))) void*)l, 16, 0, 0);
}
// XOR-swizzled LDS index for transposed [row][64] bf16 tiles (kv/attn kernels).
__device__ __forceinline__ int swz(int row, int col) {
  return row * 64 + (col ^ (row & 56));
}

// ---------------- GEMM: C[M,N] = A[M,K](bf16) * B^T[N,K](bf16) + epilogue ----------------
// Grid: blockIdx.x = n-tile (FAST — keeps A-stripe in L2 across n-sweep),
//       blockIdx.y = m-tile.
// Mainloop LDS tiles XOR-swizzled on the 16B col-block (conflict-free ds_read_b128).
// Epilogue: fragments -> swizzled LDS bf16 tile -> 8 coalesced dwordx4 stores/thread.
// E: 1 +bias->bf16, 2 +bias+res->bf16, 3 gelu->bf16, 4 +bias+res->f32,
//    5 fused qkv: N=1536, cols 0-1023 phi(elu+1), split into 3 consecutive buffers
template <int E>
__launch_bounds__(256)
__global__ void gemm_bt(const uint16_t* __restrict__ A, const uint16_t* __restrict__ BT,
                        const float* __restrict__ bias, const uint16_t* __restrict__ res,
                        void* __restrict__ outp, int M, int N, int K) {
  __shared__ __align__(16) uint16_t S[128 * 128];   // mainloop: As|Bs; epilogue: C tile
  uint16_t* As = S;
  uint16_t* Bs = S + 128 * 64;
  const int tid = threadIdx.x;
  const int lane = tid & 63, wave = tid >> 6;
  const int l15 = lane & 15, l4 = lane >> 4;
  const int m0 = blockIdx.y * 128, n0 = blockIdx.x * 128;
  const int wm = (wave >> 1) * 64, wn = (wave & 1) * 64;

  f32x4 acc[4][4];
#pragma unroll
  for (int i = 0; i < 4; ++i)
#pragma unroll
    for (int j = 0; j < 4; ++j) acc[i][j] = (f32x4){0.f, 0.f, 0.f, 0.f};

  const int srow = tid >> 3;                      // 0..31: row within 32-row slice
  const int skc  = ((tid & 7) ^ (srow & 7)) * 8;  // swizzled source col-block
  const uint16_t* ga = A  + (size_t)(m0 + srow) * K + skc;
  const uint16_t* gb = BT + (size_t)(n0 + srow) * K + skc;

  for (int kb = 0; kb < K; kb += 64) {
    __syncthreads();                 // all waves done reading previous tile
#pragma unroll
    for (int i = 0; i < 4; ++i) {    // stage A(128x64) and B^T(128x64), 16B/lane
      cp16(ga + (size_t)i * 32 * K + kb, &As[(i * 256 + wave * 64) * 8]);
      cp16(gb + (size_t)i * 32 * K + kb, &Bs[(i * 256 + wave * 64) * 8]);
    }
    __syncthreads();                 // compiler drains vmcnt before barrier
#pragma unroll
    for (int kk = 0; kk < 64; kk += 32) {
      short8 af[4], bfr[4];
#pragma unroll
      for (int i = 0; i < 4; ++i)
        af[i] = *(const short8*)&As[(wm + i * 16 + l15) * 64 +
                                    ((((kk >> 3) + l4) ^ (l15 & 7)) * 8)];
#pragma unroll
      for (int j = 0; j < 4; ++j)
        bfr[j] = *(const short8*)&Bs[(wn + j * 16 + l15) * 64 +
                                     ((((kk >> 3) + l4) ^ (l15 & 7)) * 8)];
#pragma unroll
      for (int i = 0; i < 4; ++i)
#pragma unroll
        for (int j = 0; j < 4; ++j)
          acc[i][j] = __builtin_amdgcn_mfma_f32_16x16x32_bf16(af[i], bfr[j], acc[i][j], 0, 0, 0);
    }
  }

  // ---- epilogue phase 1: bias+activation in fragment layout -> swizzled LDS (bf16)
  __syncthreads();                   // everyone done with mainloop tiles
#pragma unroll
  for (int i = 0; i < 4; ++i)
#pragma unroll
    for (int r = 0; r < 4; ++r) {
      const int lrow = wm + i * 16 + l4 * 4 + r;   // C/D: row = quad*4+reg
#pragma unroll
      for (int j = 0; j < 4; ++j) {
        const int lcol = wn + j * 16 + l15;        // C/D: col = lane&15
        float v = acc[i][j][r] + bias[n0 + lcol];
        if (E == 5) {
          if (n0 + lcol < 1024) v = v > 0.f ? v + 1.f : __expf(v);  // phi = elu+1
        } else if (E == 3) {
          v = gelu_f(v);
        }
        S[lrow * 128 + ((((lcol >> 3) ^ (lrow >> 2)) & 15) * 8) + (lcol & 7)] = f2bf(v);
      }
    }
  __syncthreads();

  // ---- epilogue phase 2: coalesced readback + residual + store (16B/lane)
  uint16_t* outb = (uint16_t*)outp;
  float* outf = (float*)outp;
  const int rr = tid >> 4;          // row within 16-row pass
  const int cb = tid & 15;          // 16B col-block
#pragma unroll
  for (int p = 0; p < 8; ++p) {
    const int lrow = p * 16 + rr;
    const int row = m0 + lrow;
    const int col0 = n0 + cb * 8;
    const uint4 d = *(const uint4*)&S[lrow * 128 + ((cb ^ (lrow >> 2)) & 15) * 8];
    if (E == 5) {
      const size_t off = (size_t)(col0 >> 9) * ((size_t)ROWST * DD) +
                         (size_t)row * DD + (col0 & 511);
      *(uint4*)&outb[off] = d;
    } else if (E == 1 || E == 3) {
      *(uint4*)&outb[(size_t)row * N + col0] = d;
    } else {
      const size_t idx = (size_t)row * N + col0;
      const uint4 rd = *(const uint4*)&res[idx];
      float a[8];
      a[0] = bf2f((uint16_t)(d.x & 0xffff)) + bf2f((uint16_t)(rd.x & 0xffff));
      a[1] = bf2f((uint16_t)(d.x >> 16))    + bf2f((uint16_t)(rd.x >> 16));
      a[2] = bf2f((uint16_t)(d.y & 0xffff)) + bf2f((uint16_t)(rd.y & 0xffff));
      a[3] = bf2f((uint16_t)(d.y >> 16))    + bf2f((uint16_t)(rd.y >> 16));
      a[4] = bf2f((uint16_t)(d.z & 0xffff)) + bf2f((uint16_t)(rd.z & 0xffff));
      a[5] = bf2f((uint16_t)(d.z >> 16))    + bf2f((uint16_t)(rd.z >> 16));
      a[6] = bf2f((uint16_t)(d.w & 0xffff)) + bf2f((uint16_t)(rd.w & 0xffff));
      a[7] = bf2f((uint16_t)(d.w >> 16))    + bf2f((uint16_t)(rd.w >> 16));
      if (E == 2) {
        uint4 o;
        o.x = (uint32_t)f2bf(a[0]) | ((uint32_t)f2bf(a[1]) << 16);
        o.y = (uint32_t)f2bf(a[2]) | ((uint32_t)f2bf(a[3]) << 16);
        o.z = (uint32_t)f2bf(a[4]) | ((uint32_t)f2bf(a[5]) << 16);
        o.w = (uint32_t)f2bf(a[6]) | ((uint32_t)f2bf(a[7]) << 16);
        *(uint4*)&outb[idx] = o;
      } else {                       // E == 4: f32 out
        *(float4*)&outf[idx]     = (float4){a[0], a[1], a[2], a[3]};
        *(float4*)&outf[idx + 4] = (float4){a[4], a[5], a[6], a[7]};
      }
    }
  }
}

// ---------------- LayerNorm: one wave per 512-elem row, out bf16 ----------------
template <int BFIN>
__launch_bounds__(256)
__global__ void ln_kernel(const void* __restrict__ inp, const float* __restrict__ gam,
                          const float* __restrict__ bet, uint16_t* __restrict__ out) {
  const int row = blockIdx.x * 4 + (threadIdx.x >> 6);
  const int lane = threadIdx.x & 63;
  const size_t base = (size_t)row * DD + lane * 8;
  float x[8];
  if (BFIN) {
    const uint4 u = *(const uint4*)((const uint16_t*)inp + base);
    x[0] = bf2f((uint16_t)(u.x & 0xffff)); x[1] = bf2f((uint16_t)(u.x >> 16));
    x[2] = bf2f((uint16_t)(u.y & 0xffff)); x[3] = bf2f((uint16_t)(u.y >> 16));
    x[4] = bf2f((uint16_t)(u.z & 0xffff)); x[5] = bf2f((uint16_t)(u.z >> 16));
    x[6] = bf2f((uint16_t)(u.w & 0xffff)); x[7] = bf2f((uint16_t)(u.w >> 16));
  } else {
    const float* f = (const float*)inp + base;
    const float4 a = *(const float4*)f;
    const float4 b = *(const float4*)(f + 4);
    x[0]=a.x; x[1]=a.y; x[2]=a.z; x[3]=a.w; x[4]=b.x; x[5]=b.y; x[6]=b.z; x[7]=b.w;
  }
  float s = 0.f, s2 = 0.f;
#pragma unroll
  for (int j = 0; j < 8; ++j) { s += x[j]; s2 += x[j] * x[j]; }
#pragma unroll
  for (int off = 32; off; off >>= 1) { s += __shfl_xor(s, off, 64); s2 += __shfl_xor(s2, off, 64); }
  const float m = s * (1.f / DD);
  const float rs = rsqrtf(s2 * (1.f / DD) - m * m + 1e-5f);
  uint16_t o[8];
#pragma unroll
  for (int j = 0; j < 8; ++j) {
    const int col = lane * 8 + j;
    o[j] = f2bf((x[j] - m) * rs * gam[col] + bet[col]);
  }
  uint4 w;
  w.x = (uint32_t)o[0] | ((uint32_t)o[1] << 16);
  w.y = (uint32_t)o[2] | ((uint32_t)o[3] << 16);
  w.z = (uint32_t)o[4] | ((uint32_t)o[5] << 16);
  w.w = (uint32_t)o[6] | ((uint32_t)o[7] << 16);
  *(uint4*)(out + base) = w;
}

// ---------------- weight transpose fp32[R,C] -> bf16[C,R] ----------------
__launch_bounds__(256)
__global__ void transpose_bf(const float* __restrict__ in, uint16_t* __restrict__ out,
                             int R, int C) {
  __shared__ float tile[32][33];
  const int tx = threadIdx.x, ty = threadIdx.y;
  const int c0 = blockIdx.x * 32, r0 = blockIdx.y * 32;
#pragma unroll
  for (int i = 0; i < 32; i += 8)
    tile[ty + i][tx] = in[(size_t)(r0 + ty + i) * C + (c0 + tx)];
  __syncthreads();
#pragma unroll
  for (int i = 0; i < 32; i += 8)
    out[(size_t)(c0 + ty + i) * R + (r0 + tx)] = f2bf(tile[tx][ty + i]);
}

__global__ void concat_bias(const float* __restrict__ bq, const float* __restrict__ bk,
                            const float* __restrict__ bv, float* __restrict__ o) {
  const int t = blockIdx.x * 256 + threadIdx.x;
  if (t < 512) o[t] = bq[t];
  else if (t < 1024) o[t] = bk[t - 512];
  else if (t < 1536) o[t] = bv[t - 1024];
}

// ---------------- kv partials via MFMA: kv[b,h,dk,dv] = sum_n pk*v ----------------
// grid (32 bh, 16 nchunk); 4 waves, each owns 256 rows in 4 transposed 64x64 LDS tiles.
// No barriers in the K-loop (wave-private tiles). Per-block partial -> ws.
__launch_bounds__(256)
__global__ void kv_mfma(const uint16_t* __restrict__ pk, const uint16_t* __restrict__ v,
                        float* __restrict__ kvp, float* __restrict__ ksp) {
  __shared__ __align__(16) uint16_t sT[4][2][64 * 64];  // [wave][pk|v][swizzled]
  __shared__ float ksred[64];
  const int bh = blockIdx.x, b = bh >> 3, h = bh & 7;
  const int t = threadIdx.x, lane = t & 63, w = t >> 6;
  const int l15 = lane & 15, l4 = lane >> 4;
  if (t < 64) ksred[t] = 0.f;
  __syncthreads();

  f32x4 acc[4][4];
#pragma unroll
  for (int i = 0; i < 4; ++i)
#pragma unroll
    for (int j = 0; j < 4; ++j) acc[i][j] = (f32x4){0.f, 0.f, 0.f, 0.f};
  float ks[4] = {0.f, 0.f, 0.f, 0.f};

  const int rl = lane >> 3, cl = (lane & 7) * 8;  // load: 8 rows x 64 cols per round
  for (int sc = 0; sc < 4; ++sc) {
    const int nbase = blockIdx.y * 1024 + w * 256 + sc * 64;
#pragma unroll
    for (int ro = 0; ro < 8; ++ro) {
      const int n = ro * 8 + rl;
      const size_t gofs = ((size_t)(b * NN + nbase + n) * HH + h) * 64 + cl;
      const short8 pv = *(const short8*)(pk + gofs);
      const short8 vv = *(const short8*)(v + gofs);
#pragma unroll
      for (int j = 0; j < 8; ++j) {           // transpose into [dk][n] / [dv][n]
        sT[w][0][swz(cl + j, n)] = (uint16_t)pv[j];
        sT[w][1][swz(cl + j, n)] = (uint16_t)vv[j];
      }
    }
#pragma unroll
    for (int kk = 0; kk < 64; kk += 32) {
      short8 af[4], bfr[4];
#pragma unroll
      for (int i = 0; i < 4; ++i)
        af[i] = *(const short8*)&sT[w][0][swz(i * 16 + l15, kk + l4 * 8)];
#pragma unroll
      for (int j = 0; j < 4; ++j)
        bfr[j] = *(const short8*)&sT[w][1][swz(j * 16 + l15, kk + l4 * 8)];
#pragma unroll
      for (int i = 0; i < 4; ++i) {
#pragma unroll
        for (int e = 0; e < 8; ++e) ks[i] += bf2f((uint16_t)af[i][e]);
#pragma unroll
        for (int j = 0; j < 4; ++j)
          acc[i][j] = __builtin_amdgcn_mfma_f32_16x16x32_bf16(af[i], bfr[j], acc[i][j], 0, 0, 0);
      }
    }
  }
  // ksum partial: reduce the 4 k-slices (quads) -> lane l4==0 holds dk=i*16+l15
#pragma unroll
  for (int i = 0; i < 4; ++i) {
    float s = ks[i];
    s += __shfl_xor(s, 16, 64); s += __shfl_xor(s, 32, 64);
    if (l4 == 0) atomicAdd(&ksred[i * 16 + l15], s);
  }
  __syncthreads();                       // everyone done with sT + ksred
  float* red = (float*)&sT[0][0][0];     // 48 KB scratch for waves 1..3
  if (w > 0) {
#pragma unroll
    for (int i = 0; i < 4; ++i)
#pragma unroll
      for (int r = 0; r < 4; ++r)
#pragma unroll
        for (int j = 0; j < 4; ++j)
          red[(w - 1) * 4096 + (i * 16 + l4 * 4 + r) * 64 + j * 16 + l15] = acc[i][j][r];
  }
  __syncthreads();
  if (w == 0) {
    float* dst = kvp + ((size_t)bh * 16 + blockIdx.y) * 4096;
#pragma unroll
    for (int i = 0; i < 4; ++i)
#pragma unroll
      for (int r = 0; r < 4; ++r)
#pragma unroll
        for (int j = 0; j < 4; ++j) {
          const int e = (i * 16 + l4 * 4 + r) * 64 + j * 16 + l15;
          dst[e] = acc[i][j][r] + red[e] + red[4096 + e] + red[8192 + e];
        }
  }
  if (t < 64) ksp[((size_t)bh * 16 + blockIdx.y) * 64 + t] = ksred[t];
}

// sum the 16 per-chunk partials. grid (32, 17): y==16 handles ksum.
__launch_bounds__(256)
__global__ void kv_reduce(const float* __restrict__ kvp, const float* __restrict__ ksp,
                          float* __restrict__ kv, float* __restrict__ ksum) {
  const int bh = blockIdx.x;
  if (blockIdx.y == 16) {
    if (threadIdx.x < 64) {
      float s = 0.f;
      for (int c = 0; c < 16; ++c) s += ksp[((size_t)bh * 16 + c) * 64 + threadIdx.x];
      ksum[bh * 64 + threadIdx.x] = s;
    }
    return;
  }
  const int e = blockIdx.y * 256 + threadIdx.x;
  float s = 0.f;
  for (int c = 0; c < 16; ++c) s += kvp[((size_t)bh * 16 + c) * 4096 + e];
  kv[(size_t)bh * 4096 + e] = s;
}

// ---------------- attn via MFMA: attn = (pq @ kv) / (pq . ksum + eps) ----------------
// grid (32 bh, 64); block 4 waves x 64 rows. A-frags direct from global (layout matches).
__launch_bounds__(256)
__global__ void attn_mfma(const uint16_t* __restrict__ pq, const float* __restrict__ kv,
                          const float* __restrict__ ksum, uint16_t* __restrict__ attn) {
  __shared__ __align__(16) uint16_t kvT[64 * 64];   // B: [dv][dk] swizzled, bf16
  __shared__ float ksS[64];
  __shared__ float denS[4][64];
  const int bh = blockIdx.x, b = bh >> 3, h = bh & 7;
  const int t = threadIdx.x, lane = t & 63, w = t >> 6;
  const int l15 = lane & 15, l4 = lane >> 4;
  const float* kvb = kv + (size_t)bh * 4096;
#pragma unroll
  for (int u = 0; u < 16; ++u) {
    const int e = u * 256 + t;                       // e = dk*64 + dv
    kvT[swz(e & 63, e >> 6)] = f2bf(kvb[e]);
  }
  if (t < 64) ksS[t] = ksum[bh * 64 + t];
  __syncthreads();

  float ksr[16];
#pragma unroll
  for (int kk2 = 0; kk2 < 2; ++kk2) {
    const float4 k0 = *(const float4*)&ksS[kk2 * 32 + l4 * 8];
    const float4 k1 = *(const float4*)&ksS[kk2 * 32 + l4 * 8 + 4];
    ksr[kk2 * 8 + 0] = k0.x; ksr[kk2 * 8 + 1] = k0.y; ksr[kk2 * 8 + 2] = k0.z; ksr[kk2 * 8 + 3] = k0.w;
    ksr[kk2 * 8 + 4] = k1.x; ksr[kk2 * 8 + 5] = k1.y; ksr[kk2 * 8 + 6] = k1.z; ksr[kk2 * 8 + 7] = k1.w;
  }
  short8 bfrg[2][4];
#pragma unroll
  for (int kk2 = 0; kk2 < 2; ++kk2)
#pragma unroll
    for (int j = 0; j < 4; ++j)
      bfrg[kk2][j] = *(const short8*)&kvT[swz(j * 16 + l15, kk2 * 32 + l4 * 8)];

  const int n0w = blockIdx.y * 256 + w * 64;
  f32x4 acc[4][4];
#pragma unroll
  for (int i = 0; i < 4; ++i)
#pragma unroll
    for (int j = 0; j < 4; ++j) acc[i][j] = (f32x4){0.f, 0.f, 0.f, 0.f};
  float den[4] = {0.f, 0.f, 0.f, 0.f};

#pragma unroll
  for (int i = 0; i < 4; ++i) {
    const int n = n0w + i * 16 + l15;
    const size_t abase = ((size_t)(b * NN + n) * HH + h) * 64 + l4 * 8;
#pragma unroll
    for (int kk2 = 0; kk2 < 2; ++kk2) {
      const short8 af = *(const short8*)(pq + abase + kk2 * 32);
#pragma unroll
      for (int e = 0; e < 8; ++e) den[i] += bf2f((uint16_t)af[e]) * ksr[kk2 * 8 + e];
#pragma unroll
      for (int j = 0; j < 4; ++j)
        acc[i][j] = __builtin_amdgcn_mfma_f32_16x16x32_bf16(af, bfrg[kk2][j], acc[i][j], 0, 0, 0);
    }
  }
#pragma unroll
  for (int i = 0; i < 4; ++i) {
    float s = den[i];
    s += __shfl_xor(s, 16, 64); s += __shfl_xor(s, 32, 64);
    if (l4 == 0) denS[w][i * 16 + l15] = s;          // same-wave LDS, in-order
  }
#pragma unroll
  for (int i = 0; i < 4; ++i)
#pragma unroll
    for (int r = 0; r < 4; ++r) {
      const float z = 1.f / (denS[w][i * 16 + l4 * 4 + r] + 1e-6f);
      const int n = n0w + i * 16 + l4 * 4 + r;
      const size_t ob = ((size_t)(b * NN + n) * HH + h) * 64;
#pragma unroll
      for (int j = 0; j < 4; ++j)
        attn[ob + j * 16 + l15] = f2bf(acc[i][j][r] * z);
    }
}

// ---------------- host launch ----------------
extern "C" void kernel_launch(void* const* d_in, const int* in_sizes, int n_in,
                              void* d_out, int out_size, void* d_ws, size_t ws_size,
                              hipStream_t stream) {
  (void)in_sizes; (void)n_in; (void)out_size;
  const float* x    = (const float*)d_in[0];
  const float* ln1g = (const float*)d_in[1];
  const float* ln1b = (const float*)d_in[2];
  const float* Wq   = (const float*)d_in[3];
  const float* bq   = (const float*)d_in[4];
  const float* Wk   = (const float*)d_in[5];
  const float* bk   = (const float*)d_in[6];
  const float* Wv   = (const float*)d_in[7];
  const float* bv   = (const float*)d_in[8];
  const float* Wo   = (const float*)d_in[9];
  const float* bo   = (const float*)d_in[10];
  const float* ln2g = (const float*)d_in[11];
  const float* ln2b = (const float*)d_in[12];
  const float* W1   = (const float*)d_in[13];
  const float* b1   = (const float*)d_in[14];
  const float* W2   = (const float*)d_in[15];
  const float* b2   = (const float*)d_in[16];

  if (ws_size < 409000000ULL) return;

  char* p = (char*)d_ws;
  auto alloc = [&](size_t bytes) -> char* {
    char* r = p; p += (bytes + 255) & ~(size_t)255; return r;
  };
  uint16_t* Hb  = (uint16_t*)alloc((size_t)ROWST * DD * 2);   // h (LN1 out)
  uint16_t* PQ  = (uint16_t*)alloc((size_t)ROWST * DD * 2);   // phi(q); later h2
  uint16_t* PK  = (uint16_t*)alloc((size_t)ROWST * DD * 2);   // phi(k); later hres  (contig after PQ)
  uint16_t* PV  = (uint16_t*)alloc((size_t)ROWST * DD * 2);   // v; later attn      (contig after PK)
  uint16_t* U   = (uint16_t*)alloc((size_t)32768 * HIDN * 2); // MLP hidden chunk (also hosts kv scratch)
  uint16_t* WqkvT = (uint16_t*)alloc((size_t)1536 * DD * 2);
  uint16_t* WoT = (uint16_t*)alloc((size_t)DD * DD * 2);
  uint16_t* W1T = (uint16_t*)alloc((size_t)HIDN * DD * 2);
  uint16_t* W2T = (uint16_t*)alloc((size_t)DD * HIDN * 2);
  float*    bqkv = (float*)alloc(1536 * 4);
  // kv scratch lives inside U (used before the MLP phase touches U)
  float* KVP = (float*)U;                  // 512*4096 fp32 = 8 MiB
  float* KSP = KVP + 512 * 4096;           // 512*64 fp32
  float* KV  = KSP + 512 * 64;             // 32*4096 fp32
  float* KS  = KV + 32 * 4096;             // 32*64 fp32

  const dim3 tb(32, 8);
  transpose_bf<<<dim3(16, 16), tb, 0, stream>>>(Wq, WqkvT, DD, DD);
  transpose_bf<<<dim3(16, 16), tb, 0, stream>>>(Wk, WqkvT + 512 * 512, DD, DD);
  transpose_bf<<<dim3(16, 16), tb, 0, stream>>>(Wv, WqkvT + 2 * 512 * 512, DD, DD);
  transpose_bf<<<dim3(16, 16), tb, 0, stream>>>(Wo, WoT, DD, DD);
  transpose_bf<<<dim3(64, 16), tb, 0, stream>>>(W1, W1T, DD, HIDN);
  transpose_bf<<<dim3(16, 64), tb, 0, stream>>>(W2, W2T, HIDN, DD);
  concat_bias<<<6, 256, 0, stream>>>(bq, bk, bv, bqkv);

  // h = LN1(x)
  ln_kernel<0><<<ROWST / 4, 256, 0, stream>>>(x, ln1g, ln1b, Hb);
  // fused qkv: [pq|pk|v] = epi(h @ Wqkv + b)   (n-tiles fastest)
  gemm_bt<5><<<dim3(12, 512), 256, 0, stream>>>(Hb, WqkvT, bqkv, nullptr, PQ, ROWST, 1536, DD);
  // kv / ksum via MFMA partials + reduce
  kv_mfma<<<dim3(32, 16), 256, 0, stream>>>(PK, PV, KVP, KSP);
  kv_reduce<<<dim3(32, 17), 256, 0, stream>>>(KVP, KSP, KV, KS);
  // attn (normalized) -> PV
  attn_mfma<<<dim3(32, 64), 256, 0, stream>>>(PQ, KV, KS, PV);
  // hres = attn@Wo + bo + h -> PK
  gemm_bt<2><<<dim3(4, 512), 256, 0, stream>>>(PV, WoT, bo, Hb, PK, ROWST, DD, DD);
  // h2 = LN2(hres) -> PQ
  ln_kernel<1><<<ROWST / 4, 256, 0, stream>>>(PK, ln2g, ln2b, PQ);
  // MLP in 2 row-chunks: out = h2 + gelu(h2@W1+b1)@W2 + b2
  for (int c = 0; c < 2; ++c) {
    const uint16_t* h2c = PQ + (size_t)c * 32768 * DD;
    gemm_bt<3><<<dim3(16, 256), 256, 0, stream>>>(h2c, W1T, b1, nullptr, U, 32768, HIDN, DD);
    gemm_bt<4><<<dim3(4, 256), 256, 0, stream>>>(U, W2T, b2, h2c,
        (float*)d_out + (size_t)c * 32768 * DD, 32768, DD, HIDN);
  }
}